// Round 1
// baseline (414.743 us; speedup 1.0000x reference)
//
#include <hip/hip_runtime.h>
#include <math.h>

#define BB 16
#define CC 64
#define NN 2048
#define KK 8
#define CAND 16          // phase-1 candidates (exact top-8 subset; validated R3/R6/R7/R10-R17)
#define QB 8             // queries per block (one per wave); keys LDS = QB*NN*4 = 64 KB
#define NT (QB * 64)     // 512 threads
#define MPW (NN / QB)    // 256 m-points per wave
#define TPW (MPW / 32)   // 8 col-tiles of 32 m-points per wave
#define DPL 32           // keys per lane in phase B

typedef unsigned long long u64;
typedef unsigned short u16;
typedef __attribute__((ext_vector_type(8)))  short short8;   // 8 bf16 = 4 VGPRs (MFMA A/B frag)
typedef __attribute__((ext_vector_type(16))) float f32x16;   // MFMA 32x32 C/D frag

// order-preserving fp32 -> u32 flip: ascending uint == ascending float
__device__ __forceinline__ unsigned ordflip(float f) {
    unsigned u = __float_as_uint(f);
    return u ^ ((u & 0x80000000u) ? 0xFFFFFFFFu : 0x80000000u);
}
// inverse (on the masked high bits): recover approximate r from a packed key
__device__ __forceinline__ float unflip(unsigned k) {
    unsigned u = k & 0xFFFFF800u;
    u ^= (u & 0x80000000u) ? 0x80000000u : 0xFFFFFFFFu;
    return __uint_as_float(u);
}

// ---- cross-lane helpers: DPP for offsets inside a 16-lane row, bpermute beyond ----
template<int C>
__device__ __forceinline__ unsigned dppu(unsigned v) {
    return (unsigned)__builtin_amdgcn_update_dpp(0, (int)v, C, 0xF, 0xF, true);
}
template<int OFF>
__device__ __forceinline__ unsigned shx(unsigned v) {
    if constexpr (OFF == 1)       return dppu<0xB1>(v);    // quad_perm xor 1
    else if constexpr (OFF == 2)  return dppu<0x4E>(v);    // quad_perm xor 2
    else if constexpr (OFF == 7)  return dppu<0x141>(v);   // row_half_mirror = xor 7
    else if constexpr (OFF == 15) return dppu<0x140>(v);   // row_mirror      = xor 15
    else return (unsigned)__shfl_xor((int)v, OFF, 64);
}
template<int C>
__device__ __forceinline__ double dppd(double v) {
    unsigned long long u = (unsigned long long)__double_as_longlong(v);
    int lo = __builtin_amdgcn_update_dpp(0, (int)(u & 0xffffffffull), C, 0xF, 0xF, true);
    int hi = __builtin_amdgcn_update_dpp(0, (int)(u >> 32),           C, 0xF, 0xF, true);
    return __longlong_as_double((long long)(((unsigned long long)(unsigned)hi << 32) | (unsigned)lo));
}

// ascending bitonic cleanup of a bitonic 16-sequence (j = 8,4,2,1)
__device__ __forceinline__ void clean16(unsigned k[CAND]) {
#define CMPEX(a_, b_) { unsigned lo = k[a_] < k[b_] ? k[a_] : k[b_]; \
                        unsigned hi = k[a_] < k[b_] ? k[b_] : k[a_]; k[a_] = lo; k[b_] = hi; }
    CMPEX(0,8) CMPEX(1,9) CMPEX(2,10) CMPEX(3,11) CMPEX(4,12) CMPEX(5,13) CMPEX(6,14) CMPEX(7,15)
    CMPEX(0,4) CMPEX(1,5) CMPEX(2,6)  CMPEX(3,7)  CMPEX(8,12) CMPEX(9,13) CMPEX(10,14) CMPEX(11,15)
    CMPEX(0,2) CMPEX(1,3) CMPEX(4,6)  CMPEX(5,7)  CMPEX(8,10) CMPEX(9,11) CMPEX(12,14) CMPEX(13,15)
    CMPEX(0,1) CMPEX(2,3) CMPEX(4,5)  CMPEX(6,7)  CMPEX(8,9)  CMPEX(10,11) CMPEX(12,13) CMPEX(14,15)
#undef CMPEX
}

// one butterfly merge step: my sorted-16 vs partner's sorted-16 -> top-16 of union, sorted
template<int OFF>
__device__ __forceinline__ void merge16(unsigned k[CAND]) {
    unsigned pk[CAND];
#pragma unroll
    for (int j = 0; j < CAND; ++j) pk[j] = shx<OFF>(k[j]);
#pragma unroll
    for (int j = 0; j < CAND; ++j) {
        unsigned b2_ = pk[CAND - 1 - j];
        k[j] = (k[j] < b2_) ? k[j] : b2_;
    }
    clean16(k);
}

// xx[b,n] = sum_c x[b,c,n]^2  (fp32 proxy only — phase 2 rescores exactly when needed)
__global__ __launch_bounds__(256) void compute_xx(const float* __restrict__ x,
                                                  float* __restrict__ xx) {
    int t = blockIdx.x * 256 + threadIdx.x;      // t in [0, B*N)
    int b = t >> 11, n = t & (NN - 1);
    const float* xb = x + b * (CC * NN) + n;
    float s = 0.f;
#pragma unroll
    for (int c = 0; c < CC; ++c) { float v = xb[c * NN]; s = fmaf(v, v, s); }
    xx[t] = s;
}

// split-bf16 transpose: xth[b][n][c] = bf16_rne(x), xtl = bf16_rne(x - hi).
// hi+lo captures ~18 mantissa bits -> proxy error ~4e-4 worst case, inside the
// existing eps floor (2e-3). Layout [n][c] makes every MFMA A/B fragment one
// contiguous 16B load (8 consecutive channels at fixed n).
__global__ __launch_bounds__(256) void prep_hilo(const float* __restrict__ x,
                                                 u16* __restrict__ xth,
                                                 u16* __restrict__ xtl) {
    const int t = blockIdx.x * 256 + threadIdx.x;   // [0, B*N)
    const int b = t >> 11, n = t & (NN - 1);
    const float* xb = x + b * (CC * NN) + n;
    u16* oh = xth + t * CC;
    u16* ol = xtl + t * CC;
#pragma unroll
    for (int c0 = 0; c0 < CC; c0 += 8) {
        unsigned hs[8], ls[8];
#pragma unroll
        for (int i = 0; i < 8; ++i) {
            const float v = xb[(c0 + i) * NN];        // coalesced across lanes (consecutive n)
            unsigned u = __float_as_uint(v);
            unsigned hb = (u + 0x7FFFu + ((u >> 16) & 1u)) >> 16;       // RNE -> bf16
            const float vl = v - __uint_as_float(hb << 16);             // exact residual
            unsigned u2 = __float_as_uint(vl);
            unsigned lb = (u2 + 0x7FFFu + ((u2 >> 16) & 1u)) >> 16;
            hs[i] = hb; ls[i] = lb;
        }
        *(uint4*)(oh + c0) = make_uint4(hs[0] | (hs[1] << 16), hs[2] | (hs[3] << 16),
                                        hs[4] | (hs[5] << 16), hs[6] | (hs[7] << 16));
        *(uint4*)(ol + c0) = make_uint4(ls[0] | (ls[1] << 16), ls[2] | (ls[3] << 16),
                                        ls[4] | (ls[5] << 16), ls[6] | (ls[7] << 16));
    }
}

// Phase A is now MFMA: per wave, 8 col-tiles of 32 m-points; A operand packs
// q_hi (rows 0-7) and q_lo (rows 8-15) so TWO B passes (m_hi, m_lo) yield the
// full split product. C/D layout (HW-verified m74/m101): col=lane&31,
// row=(reg&3)+8*(reg>>2)+4*(lane>>5) -> lane half h holds hi AND lo products
// of q=4h+r in regs r and r+4: combine is 3 in-lane adds, no shuffles.
__global__ __launch_bounds__(NT, 4) void knn_upsample(const float* __restrict__ x,
                                                      const float* __restrict__ xxg,
                                                      const u16* __restrict__ xth,
                                                      const u16* __restrict__ xtl,
                                                      float* __restrict__ out) {
    __shared__ unsigned keys[QB][NN];   // 64 KB

    const int tid  = threadIdx.x;
    const int w    = tid >> 6;                 // wave id = query id within block
    const int lane = tid & 63;
    const int blk  = blockIdx.x;

    // XCD-aware batch affinity (R13, measured: HBM fetch 38 MB -> 4.5 MB/dispatch):
    // 4096 blocks round-robin to 8 XCDs; pin XCD x to batches {2x, 2x+1}.
    const int xcd = blk & 7;
    const int j   = blk >> 3;                  // [0, 512)
    const int b   = 2 * xcd + (j >> 8);        // batch
    const int n0  = (j & 255) << 3;            // 8 consecutive queries per block
    const float* xb = x + b * (CC * NN);

    // ---------------- phase A: split-bf16 MFMA proxy distances ----------------
    const int col = lane & 31;                 // MFMA row/col index
    const int h   = lane >> 5;                 // k-half (channels 8h..8h+7 of each k-step)
    const u16* xthb = xth + b * (NN * CC);
    const u16* xtlb = xtl + b * (NN * CC);

    // A fragments (held across all tiles): rows 0-7 = q_hi, 8-15 = q_lo, 16-31 = 0.
    // Consistent (half,slot)->channel packing on A and B makes the dot product
    // invariant to the exact within-half slot order.
    short8 afrag[4];
    {
        const u16* aptr = (col < 8) ? (xthb + (n0 + col) * CC)
                                    : (xtlb + (n0 + (col & 7)) * CC);
#pragma unroll
        for (int ks = 0; ks < 4; ++ks) {
            short8 av = *(const short8*)(aptr + ks * 16 + h * 8);
            if (col >= 16) {
#pragma unroll
                for (int i2 = 0; i2 < 8; ++i2) av[i2] = 0;
            }
            afrag[ks] = av;
        }
    }

    const int mbase = w * MPW;                 // 256 m-points per wave
    const u16* bhp = xthb + (mbase + col) * CC + h * 8;
    const u16* blp = xtlb + (mbase + col) * CC + h * 8;

#pragma unroll 2
    for (int t8 = 0; t8 < TPW; ++t8) {
        f32x16 acc1, acc2;                     // acc1: q*m_hi, acc2: q*m_lo
#pragma unroll
        for (int i2 = 0; i2 < 16; ++i2) { acc1[i2] = 0.f; acc2[i2] = 0.f; }
#pragma unroll
        for (int ks = 0; ks < 4; ++ks) {       // K=64 in 4 steps of 16
            const short8 bh = *(const short8*)(bhp + t8 * (32 * CC) + ks * 16);
            const short8 bl = *(const short8*)(blp + t8 * (32 * CC) + ks * 16);
            acc1 = __builtin_amdgcn_mfma_f32_32x32x16_bf16(afrag[ks], bh, acc1, 0, 0, 0);
            acc2 = __builtin_amdgcn_mfma_f32_32x32x16_bf16(afrag[ks], bl, acc2, 0, 0, 0);
        }
        const int m = mbase + t8 * 32 + col;
        const float xxm = xxg[(b << 11) + m];
#pragma unroll
        for (int r = 0; r < 4; ++r) {
            const int q = 4 * h + r;           // lane half h owns queries 4h..4h+3
            // I = hi*hi + lo*hi + hi*lo + lo*lo  (full split product, fp32 accum)
            const float I = (acc1[r] + acc1[r + 4]) + (acc2[r] + acc2[r + 4]);
            const float rr = fmaf(-2.f, I, xxm);
            unsigned u = __float_as_uint(rr);
            u ^= ((u & 0x80000000u) ? 0xFFFFFFFFu : 0x80000000u);
            const unsigned key = (u & 0xFFFFF800u) | (unsigned)m;
            keys[q][m] = (m == n0 + q) ? 0xFFFFFFFFu : key;   // exclude self
        }
    }
    __syncthreads();

    // ---------------- phase B (verbatim): wave w selects candidates for query n = n0 + w ----------------
    const int n = n0 + w;
    unsigned key[DPL];
#pragma unroll
    for (int t = 0; t < 8; ++t) {              // contiguous uint4 reads (ds_read_b128)
        uint4 kv = *(const uint4*)(&keys[w][256 * t + 4 * lane]);
        key[4 * t] = kv.x; key[4 * t + 1] = kv.y; key[4 * t + 2] = kv.z; key[4 * t + 3] = kv.w;
    }

    // per-lane TOP-8-of-32: 4 bitonic sort-8 (asc,desc,asc,desc), discard-merge pairs,
    // final discard-merge. P(lane holds >8 of wave top-16) ~ 4e-11/query — safe.
#pragma unroll
    for (int blk4 = 0; blk4 < 4; ++blk4) {
        const int base = blk4 * 8;
        const bool asc = (blk4 & 1) == 0;
#pragma unroll
        for (int k = 2; k <= 8; k <<= 1) {
#pragma unroll
            for (int jj = k >> 1; jj > 0; jj >>= 1) {
#pragma unroll
                for (int i = 0; i < 8; ++i) {
                    int l = i ^ jj;
                    if (l > i) {
                        bool up = (((i & k) == 0) == asc);
                        unsigned a = key[base + i], b2_ = key[base + l];
                        unsigned lo = a < b2_ ? a : b2_, hi = a < b2_ ? b2_ : a;
                        key[base + i] = up ? lo : hi;
                        key[base + l] = up ? hi : lo;
                    }
                }
            }
        }
    }
#pragma unroll
    for (int i = 0; i < 8; ++i) key[i] = key[i] < key[8 + i] ? key[i] : key[8 + i];
#pragma unroll
    for (int jj = 4; jj > 0; jj >>= 1)
#pragma unroll
        for (int i = 0; i < 8; ++i) {
            int l = i ^ jj;
            if (l > i && key[l] < key[i]) { unsigned t2 = key[i]; key[i] = key[l]; key[l] = t2; }
        }
#pragma unroll
    for (int i = 0; i < 8; ++i) key[16 + i] = key[16 + i] < key[24 + i] ? key[16 + i] : key[24 + i];
#pragma unroll
    for (int jj = 4; jj > 0; jj >>= 1)
#pragma unroll
        for (int i = 0; i < 8; ++i) {
            int l = i ^ jj;
            if (l > i && key[16 + l] < key[16 + i]) { unsigned t2 = key[16 + i]; key[16 + i] = key[16 + l]; key[16 + l] = t2; }
        }
#pragma unroll
    for (int i = 0; i < 8; ++i) key[i] = key[i] < key[16 + 7 - i] ? key[i] : key[16 + 7 - i];
#pragma unroll
    for (int jj = 4; jj > 0; jj >>= 1)
#pragma unroll
        for (int i = 0; i < 8; ++i) {
            int l = i ^ jj;
            if (l > i && key[l] < key[i]) { unsigned t2 = key[i]; key[i] = key[l]; key[l] = t2; }
        }

    // butterfly step 1 (xor 1, DPP): my-8 ++ reversed partner-8 = bitonic 16 -> sorted 16
    unsigned k16[CAND];
    {
        unsigned p8[8];
#pragma unroll
        for (int jj = 0; jj < 8; ++jj) p8[jj] = shx<1>(key[jj]);
#pragma unroll
        for (int jj = 0; jj < 8; ++jj) { k16[jj] = key[jj]; k16[8 + jj] = p8[7 - jj]; }
        clean16(k16);
    }
    merge16<2>(k16);
    merge16<7>(k16);
    merge16<15>(k16);
    merge16<16>(k16);
    merge16<32>(k16);

    // extract indices; belt-and-braces lane-0 broadcast (unique keys guarantee uniformity)
    int i16[CAND];
#pragma unroll
    for (int jj = 0; jj < CAND; ++jj) i16[jj] = __shfl((int)(k16[jj] & 0x7FFu), 0, 64);

    // ---------------- gap test: can the proxy alone certify the top-8 SET? ----------------
    const float r7 = unflip(k16[7]), r8 = unflip(k16[8]);
    const float eps = fmaxf(fabsf(r7), fabsf(r8)) * 0.0009765625f + 2e-3f;  // 2^-10 rel + abs floor
    float ssum = 0.f;

    if (r8 - r7 > eps) {
        // ---- fast path: proxy top-8 is exact; 8 gathers + sum ----
#pragma unroll
        for (int jj = 0; jj < KK; ++jj) ssum += xb[lane * NN + i16[jj]];
    } else {
        // ---- slow path: exact fp64 rescore -> u64 keys -> pairwise rank ----
        const double qd = (double)xb[lane * NN + n];   // lane = channel
        u64 ke[CAND];
        float xf[CAND];
#pragma unroll
        for (int jj = 0; jj < CAND; ++jj) {
            const float xv = xb[lane * NN + i16[jj]];
            xf[jj] = xv;
            double dt = (double)xv - qd;
            double part = dt * dt;
            part += dppd<0xB1>(part);
            part += dppd<0x4E>(part);
            part += dppd<0x141>(part);
            part += dppd<0x140>(part);
            part += __shfl_xor(part, 16, 64);
            part += __shfl_xor(part, 32, 64);
            u64 eb = (u64)__double_as_longlong(part);  // identical on all lanes, >= 0
            ke[jj] = (eb & ~2047ull) | (u64)(unsigned)i16[jj];
        }
        int rank[CAND];
#pragma unroll
        for (int jj = 0; jj < CAND; ++jj) rank[jj] = 0;
#pragma unroll
        for (int jj = 0; jj < CAND; ++jj)
#pragma unroll
            for (int k2 = jj + 1; k2 < CAND; ++k2) {
                const bool jw = ke[jj] < ke[k2];
                rank[k2] += jw ? 1 : 0;
                rank[jj] += jw ? 0 : 1;
            }
#pragma unroll
        for (int jj = 0; jj < CAND; ++jj) ssum += (rank[jj] < KK) ? xf[jj] : 0.f;
    }

    float mean = ssum * 0.125f;
    float* ob = out + b * (CC * 2 * NN) + lane * (2 * NN);
    ob[n]      = xb[lane * NN + n];   // first half: copy of x
    ob[NN + n] = mean;                // second half: mean of exact 8-NN features
}

extern "C" void kernel_launch(void* const* d_in, const int* in_sizes, int n_in,
                              void* d_out, int out_size, void* d_ws, size_t ws_size,
                              hipStream_t stream) {
    (void)in_sizes; (void)n_in; (void)ws_size; (void)out_size;
    const float* x = (const float*)d_in[0];
    float* xx = (float*)d_ws;                                        // 128 KB
    u16* xth = (u16*)((char*)d_ws + (size_t)BB * NN * 4);            // 4 MB bf16-hi [b][n][c]
    u16* xtl = xth + (size_t)BB * NN * CC;                           // 4 MB bf16-lo [b][n][c]
    float* out = (float*)d_out;
    compute_xx<<<dim3(BB * NN / 256), dim3(256), 0, stream>>>(x, xx);
    prep_hilo<<<dim3(BB * NN / 256), dim3(256), 0, stream>>>(x, xth, xtl);
    knn_upsample<<<dim3(BB * NN / QB), dim3(NT), 0, stream>>>(x, xx, xth, xtl, out);
}

// Round 2
// 259.106 us; speedup vs baseline: 1.6007x; 1.6007x over previous
//
#include <hip/hip_runtime.h>
#include <math.h>

#define BB 16
#define CC 64
#define NN 2048
#define KK 8
#define CAND 16          // phase-1 candidates (exact top-8 subset; validated R3/R6/R7/R10-R17)
#define QB 8             // queries per block (one per wave); keys LDS = QB*NN*4 = 64 KB
#define NT (QB * 64)     // 512 threads
#define MPW (NN / QB)    // 256 m-points per wave
#define TPW (MPW / 32)   // 8 col-tiles of 32 m-points per wave
#define NTILE (NN / 32)  // 64 m-tiles per batch
#define DPL 32           // keys per lane in phase B

typedef unsigned long long u64;
typedef unsigned short u16;
typedef __attribute__((ext_vector_type(8)))  short short8;   // 8 bf16 = 4 VGPRs (MFMA A/B frag)
typedef __attribute__((ext_vector_type(16))) float f32x16;   // MFMA 32x32 C/D frag

// order-preserving fp32 -> u32 flip: ascending uint == ascending float
__device__ __forceinline__ unsigned ordflip(float f) {
    unsigned u = __float_as_uint(f);
    return u ^ ((u & 0x80000000u) ? 0xFFFFFFFFu : 0x80000000u);
}
// inverse (on the masked high bits): recover approximate r from a packed key
__device__ __forceinline__ float unflip(unsigned k) {
    unsigned u = k & 0xFFFFF800u;
    u ^= (u & 0x80000000u) ? 0x80000000u : 0xFFFFFFFFu;
    return __uint_as_float(u);
}

// ---- cross-lane helpers: DPP for offsets inside a 16-lane row, bpermute beyond ----
template<int C>
__device__ __forceinline__ unsigned dppu(unsigned v) {
    return (unsigned)__builtin_amdgcn_update_dpp(0, (int)v, C, 0xF, 0xF, true);
}
template<int OFF>
__device__ __forceinline__ unsigned shx(unsigned v) {
    if constexpr (OFF == 1)       return dppu<0xB1>(v);    // quad_perm xor 1
    else if constexpr (OFF == 2)  return dppu<0x4E>(v);    // quad_perm xor 2
    else if constexpr (OFF == 7)  return dppu<0x141>(v);   // row_half_mirror = xor 7
    else if constexpr (OFF == 15) return dppu<0x140>(v);   // row_mirror      = xor 15
    else return (unsigned)__shfl_xor((int)v, OFF, 64);
}
template<int C>
__device__ __forceinline__ double dppd(double v) {
    unsigned long long u = (unsigned long long)__double_as_longlong(v);
    int lo = __builtin_amdgcn_update_dpp(0, (int)(u & 0xffffffffull), C, 0xF, 0xF, true);
    int hi = __builtin_amdgcn_update_dpp(0, (int)(u >> 32),           C, 0xF, 0xF, true);
    return __longlong_as_double((long long)(((unsigned long long)(unsigned)hi << 32) | (unsigned)lo));
}

// ascending bitonic cleanup of a bitonic 16-sequence (j = 8,4,2,1)
__device__ __forceinline__ void clean16(unsigned k[CAND]) {
#define CMPEX(a_, b_) { unsigned lo = k[a_] < k[b_] ? k[a_] : k[b_]; \
                        unsigned hi = k[a_] < k[b_] ? k[b_] : k[a_]; k[a_] = lo; k[b_] = hi; }
    CMPEX(0,8) CMPEX(1,9) CMPEX(2,10) CMPEX(3,11) CMPEX(4,12) CMPEX(5,13) CMPEX(6,14) CMPEX(7,15)
    CMPEX(0,4) CMPEX(1,5) CMPEX(2,6)  CMPEX(3,7)  CMPEX(8,12) CMPEX(9,13) CMPEX(10,14) CMPEX(11,15)
    CMPEX(0,2) CMPEX(1,3) CMPEX(4,6)  CMPEX(5,7)  CMPEX(8,10) CMPEX(9,11) CMPEX(12,14) CMPEX(13,15)
    CMPEX(0,1) CMPEX(2,3) CMPEX(4,5)  CMPEX(6,7)  CMPEX(8,9)  CMPEX(10,11) CMPEX(12,13) CMPEX(14,15)
#undef CMPEX
}

// one butterfly merge step: my sorted-16 vs partner's sorted-16 -> top-16 of union, sorted
template<int OFF>
__device__ __forceinline__ void merge16(unsigned k[CAND]) {
    unsigned pk[CAND];
#pragma unroll
    for (int j = 0; j < CAND; ++j) pk[j] = shx<OFF>(k[j]);
#pragma unroll
    for (int j = 0; j < CAND; ++j) {
        unsigned b2_ = pk[CAND - 1 - j];
        k[j] = (k[j] < b2_) ? k[j] : b2_;
    }
    clean16(k);
}

// xx[b,n] = sum_c x[b,c,n]^2  (fp32 proxy only — phase 2 rescores exactly when needed)
__global__ __launch_bounds__(256) void compute_xx(const float* __restrict__ x,
                                                  float* __restrict__ xx) {
    int t = blockIdx.x * 256 + threadIdx.x;      // t in [0, B*N)
    int b = t >> 11, n = t & (NN - 1);
    const float* xb = x + b * (CC * NN) + n;
    float s = 0.f;
#pragma unroll
    for (int c = 0; c < CC; ++c) { float v = xb[c * NN]; s = fmaf(v, v, s); }
    xx[t] = s;
}

// Pre-swizzled split-bf16 MFMA operand store (R2 fix for R1's gather stall):
// bswz unit index ((b*64 + tt)*8 + p*4 + ks)*64 + lane  holds the EXACT 16B
// (8 bf16) that wave-lane `lane` consumes for m-tile tt, pass p (0=hi,1=lo),
// k-step ks: point n = tt*32 + (lane&31), channels ks*16 + (lane>>5)*8 .. +7.
// Per-lane data is bit-identical to R1 (mapping HW-verified by R1's pass);
// only the memory permutation changes -> every fragment read in the main
// kernel is one lane-linear, fully-coalesced global_load_dwordx4.
__global__ __launch_bounds__(256) void prep_bswz(const float* __restrict__ x,
                                                 u16* __restrict__ bswz) {
    const int t = blockIdx.x * 256 + threadIdx.x;   // [0, B*NTILE*8*64)
    const int lane = t & 63;
    const int ks   = (t >> 6) & 3;
    const int p    = (t >> 8) & 1;
    const int tt   = (t >> 9) & (NTILE - 1);
    const int b    = t >> 15;
    const int n    = tt * 32 + (lane & 31);
    const int c0   = ks * 16 + (lane >> 5) * 8;
    const float* src = x + b * (CC * NN) + n;
    unsigned o[8];
#pragma unroll
    for (int i = 0; i < 8; ++i) {
        const float v = src[(c0 + i) * NN];           // 32 consecutive lanes -> 128B contiguous
        unsigned u = __float_as_uint(v);
        unsigned hb = (u + 0x7FFFu + ((u >> 16) & 1u)) >> 16;       // RNE -> bf16 (hi)
        if (p == 0) {
            o[i] = hb;
        } else {
            const float vl = v - __uint_as_float(hb << 16);         // exact residual
            unsigned u2 = __float_as_uint(vl);
            o[i] = (u2 + 0x7FFFu + ((u2 >> 16) & 1u)) >> 16;        // RNE -> bf16 (lo)
        }
    }
    *(uint4*)(bswz + (size_t)t * 8) =
        make_uint4(o[0] | (o[1] << 16), o[2] | (o[3] << 16),
                   o[4] | (o[5] << 16), o[6] | (o[7] << 16));       // coalesced 16B store
}

// Phase A: split-bf16 MFMA proxy distances, operands from the pre-swizzled
// store. A operand packs q_hi (rows 0-7) and q_lo (rows 8-15); two B passes
// (m_hi, m_lo) yield the full split product. C/D layout (HW-verified
// m74/m101 + R1 pass): col=lane&31, row=(reg&3)+8*(reg>>2)+4*(lane>>5) ->
// lane half h holds hi AND lo products of q=4h+r in regs r and r+4.
__global__ __launch_bounds__(NT, 4) void knn_upsample(const float* __restrict__ x,
                                                      const float* __restrict__ xxg,
                                                      const u16* __restrict__ bswz,
                                                      float* __restrict__ out) {
    __shared__ unsigned keys[QB][NN];   // 64 KB

    const int tid  = threadIdx.x;
    const int w    = tid >> 6;                 // wave id = query id within block
    const int lane = tid & 63;
    const int blk  = blockIdx.x;

    // XCD-aware batch affinity (R13, measured: HBM fetch 38 MB -> 4.5 MB/dispatch):
    // 4096 blocks round-robin to 8 XCDs; pin XCD x to batches {2x, 2x+1}.
    const int xcd = blk & 7;
    const int j   = blk >> 3;                  // [0, 512)
    const int b   = 2 * xcd + (j >> 8);        // batch
    const int n0  = (j & 255) << 3;            // 8 consecutive queries per block
    const float* xb = x + b * (CC * NN);

    // ---------------- phase A ----------------
    const int col = lane & 31;                 // MFMA row/col index
    const int h   = lane >> 5;                 // k-half (channels 8h..8h+7 of each k-step)

    // A fragments (held across all tiles): rows 0-7 = q_hi, 8-15 = q_lo, 16-31 = 0.
    // Sourced from bswz at the queries' home tile (4 gathered loads/wave, one-time).
    short8 afrag[4];
    {
        const int qi = col & 7;                // query row within the 8-query group
        const int p  = (col >> 3) & 1;         // 0 = hi rows, 1 = lo rows (zeroed if col>=16)
        const int nq = n0 + qi;
        const u16* ap = bswz + ((((size_t)b * NTILE + (nq >> 5)) * 8 + p * 4) * 64
                                + h * 32 + (nq & 31)) * 8;
#pragma unroll
        for (int ks = 0; ks < 4; ++ks) {
            short8 av = *(const short8*)(ap + (size_t)ks * 64 * 8);
            if (col >= 16) {
#pragma unroll
                for (int i2 = 0; i2 < 8; ++i2) av[i2] = 0;
            }
            afrag[ks] = av;
        }
    }

    const int mbase = w * MPW;                 // 256 m-points per wave (tiles w*8 .. w*8+7)
    const u16* bp = bswz + (((size_t)b * NTILE + w * TPW) * 8) * 64 * 8 + lane * 8;

#pragma unroll 2
    for (int t8 = 0; t8 < TPW; ++t8) {
        f32x16 acc1, acc2;                     // acc1: q*m_hi, acc2: q*m_lo
#pragma unroll
        for (int i2 = 0; i2 < 16; ++i2) { acc1[i2] = 0.f; acc2[i2] = 0.f; }
#pragma unroll
        for (int ks = 0; ks < 4; ++ks) {       // K=64 in 4 steps of 16
            // lane-linear: one coalesced 1KB dwordx4 per wave per load
            const short8 bh = *(const short8*)(bp + ((size_t)(t8 * 8 + ks)     * 64) * 8);
            const short8 bl = *(const short8*)(bp + ((size_t)(t8 * 8 + 4 + ks) * 64) * 8);
            acc1 = __builtin_amdgcn_mfma_f32_32x32x16_bf16(afrag[ks], bh, acc1, 0, 0, 0);
            acc2 = __builtin_amdgcn_mfma_f32_32x32x16_bf16(afrag[ks], bl, acc2, 0, 0, 0);
        }
        const int m = mbase + t8 * 32 + col;
        const float xxm = xxg[(b << 11) + m];
#pragma unroll
        for (int r = 0; r < 4; ++r) {
            const int q = 4 * h + r;           // lane half h owns queries 4h..4h+3
            // I = hi*hi + lo*hi + hi*lo + lo*lo  (full split product, fp32 accum)
            const float I = (acc1[r] + acc1[r + 4]) + (acc2[r] + acc2[r + 4]);
            const float rr = fmaf(-2.f, I, xxm);
            unsigned u = __float_as_uint(rr);
            u ^= ((u & 0x80000000u) ? 0xFFFFFFFFu : 0x80000000u);
            const unsigned key = (u & 0xFFFFF800u) | (unsigned)m;
            keys[q][m] = (m == n0 + q) ? 0xFFFFFFFFu : key;   // exclude self
        }
    }
    __syncthreads();

    // ---------------- phase B (verbatim): wave w selects candidates for query n = n0 + w ----------------
    const int n = n0 + w;
    unsigned key[DPL];
#pragma unroll
    for (int t = 0; t < 8; ++t) {              // contiguous uint4 reads (ds_read_b128)
        uint4 kv = *(const uint4*)(&keys[w][256 * t + 4 * lane]);
        key[4 * t] = kv.x; key[4 * t + 1] = kv.y; key[4 * t + 2] = kv.z; key[4 * t + 3] = kv.w;
    }

    // per-lane TOP-8-of-32: 4 bitonic sort-8 (asc,desc,asc,desc), discard-merge pairs,
    // final discard-merge. P(lane holds >8 of wave top-16) ~ 4e-11/query — safe.
#pragma unroll
    for (int blk4 = 0; blk4 < 4; ++blk4) {
        const int base = blk4 * 8;
        const bool asc = (blk4 & 1) == 0;
#pragma unroll
        for (int k = 2; k <= 8; k <<= 1) {
#pragma unroll
            for (int jj = k >> 1; jj > 0; jj >>= 1) {
#pragma unroll
                for (int i = 0; i < 8; ++i) {
                    int l = i ^ jj;
                    if (l > i) {
                        bool up = (((i & k) == 0) == asc);
                        unsigned a = key[base + i], b2_ = key[base + l];
                        unsigned lo = a < b2_ ? a : b2_, hi = a < b2_ ? b2_ : a;
                        key[base + i] = up ? lo : hi;
                        key[base + l] = up ? hi : lo;
                    }
                }
            }
        }
    }
#pragma unroll
    for (int i = 0; i < 8; ++i) key[i] = key[i] < key[8 + i] ? key[i] : key[8 + i];
#pragma unroll
    for (int jj = 4; jj > 0; jj >>= 1)
#pragma unroll
        for (int i = 0; i < 8; ++i) {
            int l = i ^ jj;
            if (l > i && key[l] < key[i]) { unsigned t2 = key[i]; key[i] = key[l]; key[l] = t2; }
        }
#pragma unroll
    for (int i = 0; i < 8; ++i) key[16 + i] = key[16 + i] < key[24 + i] ? key[16 + i] : key[24 + i];
#pragma unroll
    for (int jj = 4; jj > 0; jj >>= 1)
#pragma unroll
        for (int i = 0; i < 8; ++i) {
            int l = i ^ jj;
            if (l > i && key[16 + l] < key[16 + i]) { unsigned t2 = key[16 + i]; key[16 + i] = key[16 + l]; key[16 + l] = t2; }
        }
#pragma unroll
    for (int i = 0; i < 8; ++i) key[i] = key[i] < key[16 + 7 - i] ? key[i] : key[16 + 7 - i];
#pragma unroll
    for (int jj = 4; jj > 0; jj >>= 1)
#pragma unroll
        for (int i = 0; i < 8; ++i) {
            int l = i ^ jj;
            if (l > i && key[l] < key[i]) { unsigned t2 = key[i]; key[i] = key[l]; key[l] = t2; }
        }

    // butterfly step 1 (xor 1, DPP): my-8 ++ reversed partner-8 = bitonic 16 -> sorted 16
    unsigned k16[CAND];
    {
        unsigned p8[8];
#pragma unroll
        for (int jj = 0; jj < 8; ++jj) p8[jj] = shx<1>(key[jj]);
#pragma unroll
        for (int jj = 0; jj < 8; ++jj) { k16[jj] = key[jj]; k16[8 + jj] = p8[7 - jj]; }
        clean16(k16);
    }
    merge16<2>(k16);
    merge16<7>(k16);
    merge16<15>(k16);
    merge16<16>(k16);
    merge16<32>(k16);

    // extract indices; belt-and-braces lane-0 broadcast (unique keys guarantee uniformity)
    int i16[CAND];
#pragma unroll
    for (int jj = 0; jj < CAND; ++jj) i16[jj] = __shfl((int)(k16[jj] & 0x7FFu), 0, 64);

    // ---------------- gap test: can the proxy alone certify the top-8 SET? ----------------
    const float r7 = unflip(k16[7]), r8 = unflip(k16[8]);
    const float eps = fmaxf(fabsf(r7), fabsf(r8)) * 0.0009765625f + 2e-3f;  // 2^-10 rel + abs floor
    float ssum = 0.f;

    if (r8 - r7 > eps) {
        // ---- fast path: proxy top-8 is exact; 8 gathers + sum ----
#pragma unroll
        for (int jj = 0; jj < KK; ++jj) ssum += xb[lane * NN + i16[jj]];
    } else {
        // ---- slow path: exact fp64 rescore -> u64 keys -> pairwise rank ----
        const double qd = (double)xb[lane * NN + n];   // lane = channel
        u64 ke[CAND];
        float xf[CAND];
#pragma unroll
        for (int jj = 0; jj < CAND; ++jj) {
            const float xv = xb[lane * NN + i16[jj]];
            xf[jj] = xv;
            double dt = (double)xv - qd;
            double part = dt * dt;
            part += dppd<0xB1>(part);
            part += dppd<0x4E>(part);
            part += dppd<0x141>(part);
            part += dppd<0x140>(part);
            part += __shfl_xor(part, 16, 64);
            part += __shfl_xor(part, 32, 64);
            u64 eb = (u64)__double_as_longlong(part);  // identical on all lanes, >= 0
            ke[jj] = (eb & ~2047ull) | (u64)(unsigned)i16[jj];
        }
        int rank[CAND];
#pragma unroll
        for (int jj = 0; jj < CAND; ++jj) rank[jj] = 0;
#pragma unroll
        for (int jj = 0; jj < CAND; ++jj)
#pragma unroll
            for (int k2 = jj + 1; k2 < CAND; ++k2) {
                const bool jw = ke[jj] < ke[k2];
                rank[k2] += jw ? 1 : 0;
                rank[jj] += jw ? 0 : 1;
            }
#pragma unroll
        for (int jj = 0; jj < CAND; ++jj) ssum += (rank[jj] < KK) ? xf[jj] : 0.f;
    }

    float mean = ssum * 0.125f;
    float* ob = out + b * (CC * 2 * NN) + lane * (2 * NN);
    ob[n]      = xb[lane * NN + n];   // first half: copy of x
    ob[NN + n] = mean;                // second half: mean of exact 8-NN features
}

extern "C" void kernel_launch(void* const* d_in, const int* in_sizes, int n_in,
                              void* d_out, int out_size, void* d_ws, size_t ws_size,
                              hipStream_t stream) {
    (void)in_sizes; (void)n_in; (void)ws_size; (void)out_size;
    const float* x = (const float*)d_in[0];
    float* xx = (float*)d_ws;                                        // 128 KB
    u16* bswz = (u16*)((char*)d_ws + (size_t)BB * NN * 4);           // 8 MB swizzled bf16 hi/lo
    float* out = (float*)d_out;
    compute_xx<<<dim3(BB * NN / 256), dim3(256), 0, stream>>>(x, xx);
    prep_bswz<<<dim3(BB * NTILE * 8 * 64 / 256), dim3(256), 0, stream>>>(x, bswz);
    knn_upsample<<<dim3(BB * NN / QB), dim3(NT), 0, stream>>>(x, xx, bswz, out);
}